// Round 5
// baseline (1835.856 us; speedup 1.0000x reference)
//
#include <hip/hip_runtime.h>

#define DD   32
#define BKT  128      // dsts per bucket (power of two)
#define BSH  7        // log2(BKT)
#define PCH  4096     // edges per partition/hist block
#define MAXB 2048     // padded bucket-count for scans (>= nbkt)

// ---------- bucket histogram (both relations, LDS pre-aggregated) ------------
__global__ void k_bhist(const int* __restrict__ dstA, int* __restrict__ cntA,
                        const int* __restrict__ dstB, int* __restrict__ cntB,
                        int E, int blocksPer) {
    __shared__ int h[MAXB];
    int b = blockIdx.x;
    const int* dst = (b < blocksPer) ? dstA : dstB;
    int* cnt       = (b < blocksPer) ? cntA : cntB;
    int bb         = (b < blocksPer) ? b : b - blocksPer;
    int t = threadIdx.x;
    for (int i = t; i < MAXB; i += 256) h[i] = 0;
    __syncthreads();
    int lo = bb * PCH;
    for (int k = 0; k < PCH / 256; ++k) {
        int i = lo + t + k * 256;
        if (i < E) atomicAdd(&h[dst[i] >> BSH], 1);
    }
    __syncthreads();
    for (int i = t; i < MAXB; i += 256) { int c = h[i]; if (c) atomicAdd(&cnt[i], c); }
}

// ---------- scan bucket counts -> gscan[nbkt+1] and cursor copy --------------
__global__ void k_bscan(const int* __restrict__ cntA, int* __restrict__ gsA, int* __restrict__ curA, int nbktA,
                        const int* __restrict__ cntB, int* __restrict__ gsB, int* __restrict__ curB, int nbktB) {
    __shared__ int sh[MAXB];
    __shared__ int red[256];
    int t = threadIdx.x;
    for (int sel = 0; sel < 2; ++sel) {
        const int* cnt = sel ? cntB : cntA;
        int* gs  = sel ? gsB : gsA;
        int* cur = sel ? curB : curA;
        int nbkt = sel ? nbktB : nbktA;
        for (int i = t; i < MAXB; i += 256) sh[i] = (i < nbkt) ? cnt[i] : 0;
        __syncthreads();
        int base = t * 8;
        int loc[8]; int tot = 0;
        for (int j = 0; j < 8; ++j) { loc[j] = sh[base + j]; tot += loc[j]; }
        red[t] = tot;
        __syncthreads();
        for (int off = 1; off < 256; off <<= 1) {
            int v = (t >= off) ? red[t - off] : 0;
            __syncthreads();
            red[t] += v;
            __syncthreads();
        }
        int run = red[t] - tot;   // exclusive prefix for this thread's chunk
        for (int j = 0; j < 8; ++j) { sh[base + j] = run; run += loc[j]; }
        __syncthreads();
        for (int i = t; i < nbkt; i += 256) { gs[i] = sh[i]; cur[i] = sh[i]; }
        if (t == 255) gs[nbkt] = red[255];
        __syncthreads();
    }
}

// ---------- partition: staged[pos] = (src<<BSH) | (dst & (BKT-1)) ------------
__global__ void k_part(const int* __restrict__ srcA, const int* __restrict__ dstA,
                       int* __restrict__ curA, int* __restrict__ stA,
                       const int* __restrict__ srcB, const int* __restrict__ dstB,
                       int* __restrict__ curB, int* __restrict__ stB,
                       int E, int blocksPer) {
    __shared__ int pk[PCH];
    __shared__ unsigned short bkl[PCH];
    __shared__ int hist[MAXB];
    __shared__ int basev[MAXB];
    __shared__ int gb[MAXB];
    __shared__ int red[256];
    int b = blockIdx.x;
    const int* src; const int* dst; int* cur; int* st; int bb;
    if (b < blocksPer) { src = srcA; dst = dstA; cur = curA; st = stA; bb = b; }
    else               { src = srcB; dst = dstB; cur = curB; st = stB; bb = b - blocksPer; }
    int t = threadIdx.x;
    int lo = bb * PCH;
    int cntE = E - lo; if (cntE > PCH) cntE = PCH;

    for (int i = t; i < MAXB; i += 256) hist[i] = 0;
    __syncthreads();
    for (int k = 0; k < PCH / 256; ++k) {
        int i = t + k * 256;
        if (i < cntE) atomicAdd(&hist[dst[lo + i] >> BSH], 1);
    }
    __syncthreads();
    // block-local exclusive scan of hist -> basev
    {
        int base = t * 8;
        int loc[8]; int tot = 0;
        for (int j = 0; j < 8; ++j) { loc[j] = hist[base + j]; tot += loc[j]; }
        red[t] = tot;
        __syncthreads();
        for (int off = 1; off < 256; off <<= 1) {
            int v = (t >= off) ? red[t - off] : 0;
            __syncthreads();
            red[t] += v;
            __syncthreads();
        }
        int run = red[t] - tot;
        for (int j = 0; j < 8; ++j) { basev[base + j] = run; run += loc[j]; }
    }
    __syncthreads();
    for (int i = t; i < MAXB; i += 256) hist[i] = 0;   // reuse as bump counters
    __syncthreads();
    for (int k = 0; k < PCH / 256; ++k) {
        int i = t + k * 256;
        if (i < cntE) {
            int s = src[lo + i], d = dst[lo + i];
            int bk = d >> BSH;
            int pos = basev[bk] + atomicAdd(&hist[bk], 1);
            pk[pos]  = (s << BSH) | (d & (BKT - 1));
            bkl[pos] = (unsigned short)bk;
        }
    }
    __syncthreads();
    for (int i = t; i < MAXB; i += 256) { int c = hist[i]; gb[i] = c ? atomicAdd(&cur[i], c) : 0; }
    __syncthreads();
    for (int i = t; i < cntE; i += 256) {
        int bk = bkl[i];
        st[gb[bk] + (i - basev[bk])] = pk[i];
    }
}

// ---------- bucket aggregate + fused node transform --------------------------
// block b owns dsts [b*BKT, b*BKT+BKT). Accumulate gathered src rows into LDS
// acc via ds atomics (8 lanes x float4 per edge), count degree, then
// out[v] = relu?( xdst[v]@Ws^T + b + (acc[v]/max(deg,1))@Wn^T ).
__global__ __launch_bounds__(256) void k_agg(
        const float* __restrict__ xsrc, const float* __restrict__ xdst,
        const int* __restrict__ gscan, const int* __restrict__ staged,
        const float* __restrict__ Ws, const float* __restrict__ Wn,
        const float* __restrict__ bias,
        float* __restrict__ out, int n, int do_relu) {
    __shared__ float acc[BKT * DD];
    __shared__ float deg[BKT];
    __shared__ float WsT[DD * DD], WnT[DD * DD], bsh[DD];
    __shared__ float xr[8][DD];
    int b = blockIdx.x;
    int t = threadIdx.x;
    for (int i = t; i < BKT * DD; i += 256) acc[i] = 0.f;
    for (int i = t; i < BKT; i += 256) deg[i] = 0.f;
    for (int i = t; i < DD * DD; i += 256) {
        int r = i >> 5, c = i & 31;
        WsT[c * DD + r] = Ws[i];
        WnT[c * DD + r] = Wn[i];
    }
    if (t < DD) bsh[t] = bias[t];
    __syncthreads();

    int s0 = gscan[b], s1 = gscan[b + 1];
    int g = t >> 3, q = t & 7;      // 32 edge-slots/block, 8 lanes (float4 quarters) each
    int i = s0 + g;
    for (; i + 96 < s1; i += 128) {
        int p0 = staged[i], p1 = staged[i + 32], p2 = staged[i + 64], p3 = staged[i + 96];
        float4 r0 = ((const float4*)(xsrc + (size_t)(p0 >> BSH) * DD))[q];
        float4 r1 = ((const float4*)(xsrc + (size_t)(p1 >> BSH) * DD))[q];
        float4 r2 = ((const float4*)(xsrc + (size_t)(p2 >> BSH) * DD))[q];
        float4 r3 = ((const float4*)(xsrc + (size_t)(p3 >> BSH) * DD))[q];
        int a0 = (p0 & (BKT - 1)) * DD + q * 4;
        int a1 = (p1 & (BKT - 1)) * DD + q * 4;
        int a2 = (p2 & (BKT - 1)) * DD + q * 4;
        int a3 = (p3 & (BKT - 1)) * DD + q * 4;
        atomicAdd(&acc[a0], r0.x); atomicAdd(&acc[a0 + 1], r0.y);
        atomicAdd(&acc[a0 + 2], r0.z); atomicAdd(&acc[a0 + 3], r0.w);
        atomicAdd(&acc[a1], r1.x); atomicAdd(&acc[a1 + 1], r1.y);
        atomicAdd(&acc[a1 + 2], r1.z); atomicAdd(&acc[a1 + 3], r1.w);
        atomicAdd(&acc[a2], r2.x); atomicAdd(&acc[a2 + 1], r2.y);
        atomicAdd(&acc[a2 + 2], r2.z); atomicAdd(&acc[a2 + 3], r2.w);
        atomicAdd(&acc[a3], r3.x); atomicAdd(&acc[a3 + 1], r3.y);
        atomicAdd(&acc[a3 + 2], r3.z); atomicAdd(&acc[a3 + 3], r3.w);
        if (q == 0) {
            atomicAdd(&deg[p0 & (BKT - 1)], 1.f);
            atomicAdd(&deg[p1 & (BKT - 1)], 1.f);
            atomicAdd(&deg[p2 & (BKT - 1)], 1.f);
            atomicAdd(&deg[p3 & (BKT - 1)], 1.f);
        }
    }
    for (; i < s1; i += 32) {
        int p0 = staged[i];
        float4 r0 = ((const float4*)(xsrc + (size_t)(p0 >> BSH) * DD))[q];
        int a0 = (p0 & (BKT - 1)) * DD + q * 4;
        atomicAdd(&acc[a0], r0.x); atomicAdd(&acc[a0 + 1], r0.y);
        atomicAdd(&acc[a0 + 2], r0.z); atomicAdd(&acc[a0 + 3], r0.w);
        if (q == 0) atomicAdd(&deg[p0 & (BKT - 1)], 1.f);
    }
    __syncthreads();

    int slot = t >> 5, d = t & 31;
    for (int dl0 = 0; dl0 < BKT; dl0 += 8) {
        int dl = dl0 + slot;
        int v = b * BKT + dl;
        if (v < n) {
            xr[slot][d] = xdst[(size_t)v * DD + d];
            float rinv = 1.0f / fmaxf(deg[dl], 1.0f);
            float s2 = bsh[d];
#pragma unroll
            for (int k = 0; k < DD; ++k) {
                s2 += xr[slot][k] * WsT[k * DD + d] + acc[dl * DD + k] * rinv * WnT[k * DD + d];
            }
            if (do_relu) s2 = fmaxf(s2, 0.f);
            out[(size_t)v * DD + d] = s2;
        }
    }
}

extern "C" void kernel_launch(void* const* d_in, const int* in_sizes, int n_in,
                              void* d_out, int out_size, void* d_ws, size_t ws_size,
                              hipStream_t stream) {
    const float* x_user = (const float*)d_in[0];
    const float* x_item = (const float*)d_in[1];
    const int*   ui_src = (const int*)d_in[2];
    const int*   ui_dst = (const int*)d_in[3];
    const int*   iu_src = (const int*)d_in[4];
    const int*   iu_dst = (const int*)d_in[5];
    const float* Ws_ui1 = (const float*)d_in[6];
    const float* Wn_ui1 = (const float*)d_in[7];
    const float* Ws_iu1 = (const float*)d_in[8];
    const float* Wn_iu1 = (const float*)d_in[9];
    const float* Ws_ui2 = (const float*)d_in[10];
    const float* Wn_ui2 = (const float*)d_in[11];
    const float* Ws_iu2 = (const float*)d_in[12];
    const float* Wn_iu2 = (const float*)d_in[13];
    const float* b_ui1  = (const float*)d_in[14];
    const float* b_iu1  = (const float*)d_in[15];
    const float* b_ui2  = (const float*)d_in[16];
    const float* b_iu2  = (const float*)d_in[17];

    int NU = in_sizes[0] / DD;
    int NI = in_sizes[1] / DD;
    int E  = in_sizes[2];
    int NBI = (NI + BKT - 1) >> BSH;   // item-side buckets (ui relation)
    int NBU = (NU + BKT - 1) >> BSH;   // user-side buckets (iu relation)

    // ---- workspace layout ----
    char* wp = (char*)d_ws;
    float* O_item = (float*)wp;  wp += (size_t)NI * DD * sizeof(float);
    int* st_ui    = (int*)wp;    wp += (size_t)E * sizeof(int);
    int* st_iu    = (int*)wp;    wp += (size_t)E * sizeof(int);
    int* cntI     = (int*)wp;    wp += (size_t)MAXB * sizeof(int);
    int* cntU     = (int*)wp;    wp += (size_t)MAXB * sizeof(int);
    int* gsI      = (int*)wp;    wp += (size_t)(MAXB + 1) * sizeof(int);
    int* gsU      = (int*)wp;    wp += (size_t)(MAXB + 1) * sizeof(int);
    int* curI     = (int*)wp;    wp += (size_t)MAXB * sizeof(int);
    int* curU     = (int*)wp;

    float* h_user = (float*)d_out;
    float* h_item = h_user + (size_t)NU * DD;

    int EB = (E + PCH - 1) / PCH;

    // ---- build bucket-staged edge lists (once, reused by both layers) ----
    (void)hipMemsetAsync(cntI, 0, (size_t)2 * MAXB * sizeof(int), stream);
    hipLaunchKernelGGL(k_bhist, dim3(2 * EB), dim3(256), 0, stream,
                       ui_dst, cntI, iu_dst, cntU, E, EB);
    hipLaunchKernelGGL(k_bscan, dim3(1), dim3(256), 0, stream,
                       cntI, gsI, curI, NBI, cntU, gsU, curU, NBU);
    hipLaunchKernelGGL(k_part, dim3(2 * EB), dim3(256), 0, stream,
                       ui_src, ui_dst, curI, st_ui,
                       iu_src, iu_dst, curU, st_iu, E, EB);

    // ---- layer 1 (relu) ----
    hipLaunchKernelGGL(k_agg, dim3(NBI), dim3(256), 0, stream,
                       x_user, x_item, gsI, st_ui, Ws_ui1, Wn_ui1, b_ui1, h_item, NI, 1);
    hipLaunchKernelGGL(k_agg, dim3(NBU), dim3(256), 0, stream,
                       x_item, x_user, gsU, st_iu, Ws_iu1, Wn_iu1, b_iu1, h_user, NU, 1);

    // ---- layer 2 (no relu); o_item to ws first (h_user gather still needs h_item? no:
    // o_item reads h_user; o_user writes h_user -> keep this order, sequential on stream)
    hipLaunchKernelGGL(k_agg, dim3(NBI), dim3(256), 0, stream,
                       h_user, h_item, gsI, st_ui, Ws_ui2, Wn_ui2, b_ui2, O_item, NI, 0);
    hipLaunchKernelGGL(k_agg, dim3(NBU), dim3(256), 0, stream,
                       h_item, h_user, gsU, st_iu, Ws_iu2, Wn_iu2, b_iu2, h_user, NU, 0);

    (void)hipMemcpyAsync(h_item, O_item, (size_t)NI * DD * sizeof(float),
                         hipMemcpyDeviceToDevice, stream);
}

// Round 6
// 676.581 us; speedup vs baseline: 2.7134x; 2.7134x over previous
//
#include <hip/hip_runtime.h>

#define DD   32
#define BKT  128      // dsts per bucket (power of two)
#define BSH  7        // log2(BKT)
#define PCH  4096     // edges per partition/hist block
#define MAXB 2048     // padded bucket-count (>= nbkt)
#define NB   256      // scan blocks per array
#define NT   256      // scan threads per block
#define SORTCAP 8192  // max edges per bucket for in-place sort (mean ~1280)

// ---------- bucket histogram (both relations, LDS pre-aggregated) ------------
__global__ void k_bhist(const int* __restrict__ dstA, int* __restrict__ cntA,
                        const int* __restrict__ dstB, int* __restrict__ cntB,
                        int E, int blocksPer) {
    __shared__ int h[MAXB];
    int b = blockIdx.x;
    const int* dst = (b < blocksPer) ? dstA : dstB;
    int* cnt       = (b < blocksPer) ? cntA : cntB;
    int bb         = (b < blocksPer) ? b : b - blocksPer;
    int t = threadIdx.x;
    for (int i = t; i < MAXB; i += 256) h[i] = 0;
    __syncthreads();
    int lo = bb * PCH;
    for (int k = 0; k < PCH / 256; ++k) {
        int i = lo + t + k * 256;
        if (i < E) atomicAdd(&h[dst[i] >> BSH], 1);
    }
    __syncthreads();
    for (int i = t; i < MAXB; i += 256) { int c = h[i]; if (c) atomicAdd(&cnt[i], c); }
}

// ---------- scan bucket counts -> gscan[nbkt+1] and cursor copy --------------
__global__ void k_bscan(const int* __restrict__ cntA, int* __restrict__ gsA, int* __restrict__ curA, int nbktA,
                        const int* __restrict__ cntB, int* __restrict__ gsB, int* __restrict__ curB, int nbktB) {
    __shared__ int sh[MAXB];
    __shared__ int red[256];
    int t = threadIdx.x;
    for (int sel = 0; sel < 2; ++sel) {
        const int* cnt = sel ? cntB : cntA;
        int* gs  = sel ? gsB : gsA;
        int* cur = sel ? curB : curA;
        int nbkt = sel ? nbktB : nbktA;
        for (int i = t; i < MAXB; i += 256) sh[i] = (i < nbkt) ? cnt[i] : 0;
        __syncthreads();
        int base = t * 8;
        int loc[8]; int tot = 0;
        for (int j = 0; j < 8; ++j) { loc[j] = sh[base + j]; tot += loc[j]; }
        red[t] = tot;
        __syncthreads();
        for (int off = 1; off < 256; off <<= 1) {
            int v = (t >= off) ? red[t - off] : 0;
            __syncthreads();
            red[t] += v;
            __syncthreads();
        }
        int run = red[t] - tot;
        for (int j = 0; j < 8; ++j) { sh[base + j] = run; run += loc[j]; }
        __syncthreads();
        for (int i = t; i < nbkt; i += 256) { gs[i] = sh[i]; cur[i] = sh[i]; }
        if (t == 255) gs[nbkt] = red[255];
        __syncthreads();
    }
}

// ---------- partition: staged[pos] = (src<<BSH) | (dst & (BKT-1)) ------------
// staged target is the csr buffer (later sorted in place to true CSR)
__global__ void k_part(const int* __restrict__ srcA, const int* __restrict__ dstA,
                       int* __restrict__ curA, int* __restrict__ stA,
                       const int* __restrict__ srcB, const int* __restrict__ dstB,
                       int* __restrict__ curB, int* __restrict__ stB,
                       int E, int blocksPer) {
    __shared__ int pk[PCH];
    __shared__ unsigned short bkl[PCH];
    __shared__ int hist[MAXB];
    __shared__ int basev[MAXB];
    __shared__ int gb[MAXB];
    __shared__ int red[256];
    int b = blockIdx.x;
    const int* src; const int* dst; int* cur; int* st; int bb;
    if (b < blocksPer) { src = srcA; dst = dstA; cur = curA; st = stA; bb = b; }
    else               { src = srcB; dst = dstB; cur = curB; st = stB; bb = b - blocksPer; }
    int t = threadIdx.x;
    int lo = bb * PCH;
    int cntE = E - lo; if (cntE > PCH) cntE = PCH;

    for (int i = t; i < MAXB; i += 256) hist[i] = 0;
    __syncthreads();
    for (int k = 0; k < PCH / 256; ++k) {
        int i = t + k * 256;
        if (i < cntE) atomicAdd(&hist[dst[lo + i] >> BSH], 1);
    }
    __syncthreads();
    {   // block-local exclusive scan of hist -> basev
        int base = t * 8;
        int loc[8]; int tot = 0;
        for (int j = 0; j < 8; ++j) { loc[j] = hist[base + j]; tot += loc[j]; }
        red[t] = tot;
        __syncthreads();
        for (int off = 1; off < 256; off <<= 1) {
            int v = (t >= off) ? red[t - off] : 0;
            __syncthreads();
            red[t] += v;
            __syncthreads();
        }
        int run = red[t] - tot;
        for (int j = 0; j < 8; ++j) { basev[base + j] = run; run += loc[j]; }
    }
    __syncthreads();
    for (int i = t; i < MAXB; i += 256) hist[i] = 0;   // reuse as bump counters
    __syncthreads();
    for (int k = 0; k < PCH / 256; ++k) {
        int i = t + k * 256;
        if (i < cntE) {
            int s = src[lo + i], d = dst[lo + i];
            int bk = d >> BSH;
            int pos = basev[bk] + atomicAdd(&hist[bk], 1);
            pk[pos]  = (s << BSH) | (d & (BKT - 1));
            bkl[pos] = (unsigned short)bk;
        }
    }
    __syncthreads();
    for (int i = t; i < MAXB; i += 256) { int c = hist[i]; gb[i] = c ? atomicAdd(&cur[i], c) : 0; }
    __syncthreads();
    for (int i = t; i < cntE; i += 256) {
        int bk = bkl[i];
        st[gb[bk] + (i - basev[bk])] = pk[i];
    }
}

// ---------- per-dst degree from staged bucket lists --------------------------
__global__ void k_dhist2(const int* __restrict__ gsA, const int* __restrict__ stA,
                         int* __restrict__ cntA, int nA, int nbA,
                         const int* __restrict__ gsB, const int* __restrict__ stB,
                         int* __restrict__ cntB, int nB) {
    __shared__ int h[BKT];
    int b = blockIdx.x;
    const int* gs; const int* st; int* cnt; int n; int bb;
    if (b < nbA) { gs = gsA; st = stA; cnt = cntA; n = nA; bb = b; }
    else         { gs = gsB; st = stB; cnt = cntB; n = nB; bb = b - nbA; }
    int t = threadIdx.x;
    if (t < BKT) h[t] = 0;
    __syncthreads();
    int s0 = gs[bb], s1 = gs[bb + 1];
    for (int i = s0 + t; i < s1; i += 256) atomicAdd(&h[st[i] & (BKT - 1)], 1);
    __syncthreads();
    if (t < BKT) { int v = bb * BKT + t; if (v < n) cnt[v] = h[t]; }
}

// ---------- scan pass 1/2/3 over per-dst counts -> rowptr --------------------
__global__ void k_scan_partial(const int* __restrict__ cntA, int nA,
                               const int* __restrict__ cntB, int nB,
                               int* __restrict__ tsum, int* __restrict__ bsum) {
    __shared__ int red[NT];
    int sel = blockIdx.x / NB;
    int b   = blockIdx.x % NB;
    const int* cnt = sel ? cntB : cntA;
    int n = sel ? nB : nA;
    int sub = (n + NB * NT - 1) / (NB * NT);
    int t = threadIdx.x;
    int gt = b * NT + t;
    long long lo = (long long)gt * sub;
    int s = 0;
    for (int i = 0; i < sub; ++i) {
        long long idx = lo + i;
        if (idx < n) s += cnt[idx];
    }
    tsum[(size_t)sel * NB * NT + gt] = s;
    red[t] = s;
    __syncthreads();
    for (int off = NT / 2; off > 0; off >>= 1) {
        if (t < off) red[t] += red[t + off];
        __syncthreads();
    }
    if (t == 0) bsum[sel * NB + b] = red[0];
}

__global__ void k_scan_bsum(int* __restrict__ bsum) {
    __shared__ int sh[NB];
    int t = threadIdx.x;
    for (int sel = 0; sel < 2; ++sel) {
        int v = bsum[sel * NB + t];
        sh[t] = v;
        __syncthreads();
        for (int off = 1; off < NB; off <<= 1) {
            int u = (t >= off) ? sh[t - off] : 0;
            __syncthreads();
            sh[t] += u;
            __syncthreads();
        }
        bsum[sel * NB + t] = sh[t] - v;
        __syncthreads();
    }
}

__global__ void k_scan_write(const int* __restrict__ cntA, int nA, int* __restrict__ rpA,
                             const int* __restrict__ cntB, int nB, int* __restrict__ rpB,
                             const int* __restrict__ tsum, const int* __restrict__ bsum) {
    __shared__ int sh[NT];
    int sel = blockIdx.x / NB;
    int b   = blockIdx.x % NB;
    const int* cnt = sel ? cntB : cntA;
    int* rp = sel ? rpB : rpA;
    int n = sel ? nB : nA;
    int sub = (n + NB * NT - 1) / (NB * NT);
    int t = threadIdx.x;
    int gt = b * NT + t;
    int v = tsum[(size_t)sel * NB * NT + gt];
    sh[t] = v;
    __syncthreads();
    for (int off = 1; off < NT; off <<= 1) {
        int u = (t >= off) ? sh[t - off] : 0;
        __syncthreads();
        sh[t] += u;
        __syncthreads();
    }
    int base = bsum[sel * NB + b] + sh[t] - v;
    long long lo = (long long)gt * sub;
    long long hi = lo + sub; if (hi > n) hi = n;
    for (long long i = lo; i < hi; ++i) { int c = cnt[i]; rp[i] = base; base += c; }
    if (lo < n && hi == n) rp[n] = base;
}

// ---------- in-place bucket sort: staged (bucket-grouped) -> exact CSR -------
// rowptr[bucket start] == gscan[bucket], so all writes stay inside [s0,s1).
__global__ __launch_bounds__(256) void k_bsort2(
        const int* __restrict__ gsA, const int* __restrict__ rpA, int* __restrict__ csrA,
        int nA, int nbA,
        const int* __restrict__ gsB, const int* __restrict__ rpB, int* __restrict__ csrB,
        int nB) {
    __shared__ int buf[SORTCAP];
    __shared__ int cur[BKT];
    int b = blockIdx.x;
    const int* gs; const int* rp; int* csr; int n; int bb;
    if (b < nbA) { gs = gsA; rp = rpA; csr = csrA; n = nA; bb = b; }
    else         { gs = gsB; rp = rpB; csr = csrB; n = nB; bb = b - nbA; }
    int t = threadIdx.x;
    int s0 = gs[bb], s1 = gs[bb + 1];
    int cnt = s1 - s0;
    for (int i = t; i < cnt; i += 256) buf[i] = csr[s0 + i];
    if (t < BKT) { int v = bb * BKT + t; cur[t] = (v < n) ? rp[v] : 0; }
    __syncthreads();
    for (int i = t; i < cnt; i += 256) {
        int p = buf[i];
        int pos = atomicAdd(&cur[p & (BKT - 1)], 1);
        csr[pos] = p >> BSH;
    }
}

// ---------- fused: out[v] = relu?( xdst[v]@Ws^T + b + mean gather @ Wn^T ) ----
__global__ void k_fused(const float* __restrict__ xsrc, const float* __restrict__ xdst,
                        const int* __restrict__ rowptr, const int* __restrict__ csr_src,
                        const float* __restrict__ Ws, const float* __restrict__ Wn,
                        const float* __restrict__ b,
                        float* __restrict__ out, int n, int do_relu) {
    __shared__ float WsT[DD * DD], WnT[DD * DD], bsh[DD];
    __shared__ float xrow[8][DD], mrow[8][DD];
    int tid = threadIdx.x;
    for (int i = tid; i < DD * DD; i += 256) {
        int r = i >> 5, c = i & 31;
        WsT[c * DD + r] = Ws[i];
        WnT[c * DD + r] = Wn[i];
    }
    if (tid < DD) bsh[tid] = b[tid];
    int g = tid >> 5;
    int d = tid & 31;
    int v = blockIdx.x * 8 + g;
    if (v < n) {
        int rs = rowptr[v], re = rowptr[v + 1];
        int el = d >> 3;   // edge slot 0..3
        int q  = d & 7;    // float4 quarter 0..7
        float ax = 0.f, ay = 0.f, az = 0.f, aw = 0.f;
        for (int j0 = rs; j0 < re; j0 += 32) {
            int nj = re - j0; if (nj > 32) nj = 32;
            int myi = (d < nj) ? csr_src[j0 + d] : 0;
            for (int c0 = 0; c0 < nj; c0 += 4) {
                int jj = c0 + el;
                int s = __shfl(myi, jj, 32);
                if (jj < nj) {
                    const float4* row = (const float4*)(xsrc + (size_t)s * DD);
                    float4 x4 = row[q];
                    ax += x4.x; ay += x4.y; az += x4.z; aw += x4.w;
                }
            }
        }
        ax += __shfl_xor(ax, 8, 32);  ay += __shfl_xor(ay, 8, 32);
        az += __shfl_xor(az, 8, 32);  aw += __shfl_xor(aw, 8, 32);
        ax += __shfl_xor(ax, 16, 32); ay += __shfl_xor(ay, 16, 32);
        az += __shfl_xor(az, 16, 32); aw += __shfl_xor(aw, 16, 32);
        float degf = (float)(re - rs);
        float rinv = 1.0f / fmaxf(degf, 1.0f);
        if (el == 0) {
            float4 m4; m4.x = ax * rinv; m4.y = ay * rinv; m4.z = az * rinv; m4.w = aw * rinv;
            ((float4*)(&mrow[g][0]))[q] = m4;
        }
        xrow[g][d] = xdst[(size_t)v * DD + d];
    }
    __syncthreads();
    if (v < n) {
        float s2 = bsh[d];
#pragma unroll
        for (int k = 0; k < DD; ++k) {
            s2 += xrow[g][k] * WsT[k * DD + d] + mrow[g][k] * WnT[k * DD + d];
        }
        if (do_relu) s2 = fmaxf(s2, 0.f);
        out[(size_t)v * DD + d] = s2;
    }
}

extern "C" void kernel_launch(void* const* d_in, const int* in_sizes, int n_in,
                              void* d_out, int out_size, void* d_ws, size_t ws_size,
                              hipStream_t stream) {
    const float* x_user = (const float*)d_in[0];
    const float* x_item = (const float*)d_in[1];
    const int*   ui_src = (const int*)d_in[2];
    const int*   ui_dst = (const int*)d_in[3];
    const int*   iu_src = (const int*)d_in[4];
    const int*   iu_dst = (const int*)d_in[5];
    const float* Ws_ui1 = (const float*)d_in[6];
    const float* Wn_ui1 = (const float*)d_in[7];
    const float* Ws_iu1 = (const float*)d_in[8];
    const float* Wn_iu1 = (const float*)d_in[9];
    const float* Ws_ui2 = (const float*)d_in[10];
    const float* Wn_ui2 = (const float*)d_in[11];
    const float* Ws_iu2 = (const float*)d_in[12];
    const float* Wn_iu2 = (const float*)d_in[13];
    const float* b_ui1  = (const float*)d_in[14];
    const float* b_iu1  = (const float*)d_in[15];
    const float* b_ui2  = (const float*)d_in[16];
    const float* b_iu2  = (const float*)d_in[17];

    int NU = in_sizes[0] / DD;
    int NI = in_sizes[1] / DD;
    int E  = in_sizes[2];
    int NBI = (NI + BKT - 1) >> BSH;
    int NBU = (NU + BKT - 1) >> BSH;
    int NMAX = (NU > NI) ? NU : NI;

    // ---- persistent workspace ----
    char* wp = (char*)d_ws;
    float* O_item = (float*)wp;  wp += (size_t)NI * DD * sizeof(float);
    int* csr_ui   = (int*)wp;    wp += (size_t)E * sizeof(int);
    int* csr_iu   = (int*)wp;    wp += (size_t)E * sizeof(int);
    int* rp_item  = (int*)wp;    wp += (size_t)(NI + 1) * sizeof(int);
    int* rp_user  = (int*)wp;

    // ---- transient arrays alias O_item (dead until layer 2) ----
    int* tr = (int*)O_item;
    int* bcntI = tr;  tr += MAXB;
    int* bcntU = tr;  tr += MAXB;
    int* gsI   = tr;  tr += MAXB + 1;
    int* gsU   = tr;  tr += MAXB + 1;
    int* curI  = tr;  tr += MAXB;
    int* curU  = tr;  tr += MAXB;
    int* cntI  = tr;  tr += NMAX;
    int* cntU  = tr;  tr += NMAX;
    int* tsum  = tr;  tr += 2 * NB * NT;
    int* bsum  = tr;

    float* h_user = (float*)d_out;
    float* h_item = h_user + (size_t)NU * DD;

    int EB = (E + PCH - 1) / PCH;

    // ---- CSR build: bucket partition -> per-dst counts -> scan -> local sort
    (void)hipMemsetAsync(bcntI, 0, (size_t)2 * MAXB * sizeof(int), stream);
    hipLaunchKernelGGL(k_bhist, dim3(2 * EB), dim3(256), 0, stream,
                       ui_dst, bcntI, iu_dst, bcntU, E, EB);
    hipLaunchKernelGGL(k_bscan, dim3(1), dim3(256), 0, stream,
                       bcntI, gsI, curI, NBI, bcntU, gsU, curU, NBU);
    hipLaunchKernelGGL(k_part, dim3(2 * EB), dim3(256), 0, stream,
                       ui_src, ui_dst, curI, csr_ui,
                       iu_src, iu_dst, curU, csr_iu, E, EB);
    hipLaunchKernelGGL(k_dhist2, dim3(NBI + NBU), dim3(256), 0, stream,
                       gsI, csr_ui, cntI, NI, NBI, gsU, csr_iu, cntU, NU);
    hipLaunchKernelGGL(k_scan_partial, dim3(2 * NB), dim3(NT), 0, stream,
                       cntI, NI, cntU, NU, tsum, bsum);
    hipLaunchKernelGGL(k_scan_bsum, dim3(1), dim3(NB), 0, stream, bsum);
    hipLaunchKernelGGL(k_scan_write, dim3(2 * NB), dim3(NT), 0, stream,
                       cntI, NI, rp_item, cntU, NU, rp_user, tsum, bsum);
    hipLaunchKernelGGL(k_bsort2, dim3(NBI + NBU), dim3(256), 0, stream,
                       gsI, rp_item, csr_ui, NI, NBI, gsU, rp_user, csr_iu, NU);

    // ---- layer 1 (relu) ----
    hipLaunchKernelGGL(k_fused, dim3((NI + 7) / 8), dim3(256), 0, stream,
                       x_user, x_item, rp_item, csr_ui, Ws_ui1, Wn_ui1, b_ui1,
                       h_item, NI, 1);
    hipLaunchKernelGGL(k_fused, dim3((NU + 7) / 8), dim3(256), 0, stream,
                       x_item, x_user, rp_user, csr_iu, Ws_iu1, Wn_iu1, b_iu1,
                       h_user, NU, 1);

    // ---- layer 2 (no relu) ----
    hipLaunchKernelGGL(k_fused, dim3((NI + 7) / 8), dim3(256), 0, stream,
                       h_user, h_item, rp_item, csr_ui, Ws_ui2, Wn_ui2, b_ui2,
                       O_item, NI, 0);
    hipLaunchKernelGGL(k_fused, dim3((NU + 7) / 8), dim3(256), 0, stream,
                       h_item, h_user, rp_user, csr_iu, Ws_iu2, Wn_iu2, b_iu2,
                       h_user, NU, 0);

    (void)hipMemcpyAsync(h_item, O_item, (size_t)NI * DD * sizeof(float),
                         hipMemcpyDeviceToDevice, stream);
}